// Round 2
// baseline (494.578 us; speedup 1.0000x reference)
//
#include <hip/hip_runtime.h>
#include <cstdint>
#include <cstddef>

#define CC   96
#define BB   32
#define HHn  112
#define WWn  112
#define HWn  (HHn*WWn)        // 12544
#define NPIX (BB*HWn)         // 401408
#define EPSf 1e-5f

// ---------------- w_mix transpose: wT[c*96+o] = w[o*96+c] ----------------
__global__ __launch_bounds__(256) void k_transpose(const float* __restrict__ w,
                                                   float* __restrict__ wT) {
  int i = blockIdx.x * 256 + threadIdx.x;
  if (i < CC * CC) {
    int o = i / CC, c = i % CC;
    wT[c * CC + o] = w[i];
  }
}

// ---------------- fused depthwise 7x7 conv + 1x1 mix ----------------
// One block = one 16x16 pixel tile of one image. Each thread owns 1 pixel and
// accumulates acc[96] (all output channels for that pixel) in VGPRs.
// Per channel: 22x22 x-halo staged in LDS (double-buffered), 49 LDS-FMA conv
// (weights via wave-uniform scalar loads), 96 FMA mix (wT row contiguous
// scalar loads). bias is skipped: BN(affine=False) cancels any per-channel
// constant shift exactly.
__global__ __launch_bounds__(256) void k_fused(const float* __restrict__ x,
                                               const float* __restrict__ hk,
                                               const float* __restrict__ wT,
                                               float* __restrict__ mixed) {
  // halo: 22 rows x 22 cols, row stride 24 (2-way bank alias only -> free).
  // padded to 24 rows so unguarded i1 writes land in never-read padding.
  __shared__ float halo[2][24 * 24];

  int bid = blockIdx.x;
  // XCD swizzle: 196 consecutive logical tiles per XCD -> adjacent w-tiles
  // share an L2 (store write-combining + halo row reuse).
  int logical = (bid & 7) * 196 + (bid >> 3);
  int b  = logical / 49;
  int t  = logical % 49;
  int h0 = (t / 7) * 16, w0 = (t % 7) * 16;

  int tid = threadIdx.x;
  int ph = tid >> 4, pw = tid & 15;

  // two halo-load slots per thread (484 real elements)
  int i0 = tid, i1 = tid + 256;
  int r0 = i0 / 22, c0 = i0 % 22;
  int r1 = i1 / 22, c1 = i1 % 22;
  int gh0 = h0 - 3 + r0, gw0 = w0 - 3 + c0;
  int gh1 = h0 - 3 + r1, gw1 = w0 - 3 + c1;
  bool ok0 = ((unsigned)gh0 < HHn) && ((unsigned)gw0 < WWn);
  bool ok1 = ((unsigned)gh1 < HHn) && ((unsigned)gw1 < WWn);
  long off0 = (long)gh0 * WWn + gw0;
  long off1 = (long)gh1 * WWn + gw1;

  const float* xb = x + (long)b * CC * HWn;

  float acc[CC];
#pragma unroll
  for (int o = 0; o < CC; ++o) acc[o] = 0.f;

  // preload channel 0 halo
  {
    float v0 = ok0 ? xb[off0] : 0.f;
    float v1 = ok1 ? xb[off1] : 0.f;
    halo[0][r0 * 24 + c0] = v0;
    halo[0][r1 * 24 + c1] = v1;   // i1>=484 lands in padding rows (unread)
  }
  __syncthreads();

  for (int c = 0; c < CC; ++c) {
    int cur = c & 1;
    // issue next channel's halo loads early (latency hidden under compute)
    float v0 = 0.f, v1 = 0.f;
    if (c + 1 < CC) {
      const float* xc = xb + (long)(c + 1) * HWn;
      v0 = ok0 ? xc[off0] : 0.f;
      v1 = ok1 ? xc[off1] : 0.f;
    }

    // conv: 7 independent row chains for ILP
    const float* kc = hk + c * 49;            // wave-uniform -> s_loads
    const float* hb = &halo[cur][ph * 24 + pw];
    float rs[7];
#pragma unroll
    for (int kh = 0; kh < 7; ++kh) {
      float s = 0.f;
#pragma unroll
      for (int kw = 0; kw < 7; ++kw)
        s = fmaf(hb[kh * 24 + kw], kc[kh * 7 + kw], s);
      rs[kh] = s;
    }
    float f = ((rs[0] + rs[1]) + (rs[2] + rs[3])) + ((rs[4] + rs[5]) + rs[6]);

    // mix: wT row is contiguous -> s_load_dwordx8 bursts
    const float* wc = wT + c * CC;
#pragma unroll
    for (int o = 0; o < CC; ++o) acc[o] = fmaf(f, wc[o], acc[o]);

    if (c + 1 < CC) {
      halo[cur ^ 1][r0 * 24 + c0] = v0;
      halo[cur ^ 1][r1 * 24 + c1] = v1;
    }
    __syncthreads();
  }

  float* mb = mixed + (long)b * CC * HWn + (long)(h0 + ph) * WWn + (w0 + pw);
#pragma unroll
  for (int o = 0; o < CC; ++o) mb[(long)o * HWn] = acc[o];
}

// ---------------- per-channel sum / sumsq over (b,h,w) ----------------
__global__ __launch_bounds__(256) void k_stats(const float* __restrict__ mixed,
                                               float* __restrict__ ssum,
                                               float* __restrict__ ssq) {
  int b = blockIdx.x;   // 32
  int o = blockIdx.y;   // 96
  const float4* p4 = (const float4*)(mixed + ((long)b * CC + o) * HWn);
  float s = 0.f, q = 0.f;
  for (int i = threadIdx.x; i < HWn / 4; i += 256) {
    float4 v = p4[i];
    s += v.x + v.y + v.z + v.w;
    q += v.x * v.x + v.y * v.y + v.z * v.z + v.w * v.w;
  }
  __shared__ float ls[256], lq[256];
  ls[threadIdx.x] = s; lq[threadIdx.x] = q;
  __syncthreads();
  for (int st = 128; st > 0; st >>= 1) {
    if (threadIdx.x < st) {
      ls[threadIdx.x] += ls[threadIdx.x + st];
      lq[threadIdx.x] += lq[threadIdx.x + st];
    }
    __syncthreads();
  }
  if (threadIdx.x == 0) {
    atomicAdd(&ssum[o], ls[0]);
    atomicAdd(&ssq[o], lq[0]);
  }
}

__global__ void k_finalize(const float* __restrict__ ssum,
                           const float* __restrict__ ssq,
                           float* __restrict__ meanv,
                           float* __restrict__ rstdv) {
  int o = threadIdx.x;
  if (o < CC) {
    float m = ssum[o] * (1.0f / NPIX);
    float v = ssq[o] * (1.0f / NPIX) - m * m;
    meanv[o] = m;
    rstdv[o] = 1.0f / sqrtf(v + EPSf);
  }
}

// ---------------- BN (affine=False) + exact GELU ----------------
__global__ __launch_bounds__(256) void k_bngelu(const float* __restrict__ mixed,
                                                const float* __restrict__ meanv,
                                                const float* __restrict__ rstdv,
                                                float* __restrict__ out) {
  long i4 = (long)blockIdx.x * 256 + threadIdx.x;
  long e = i4 * 4;
  int o = (int)((e / HWn) % CC);       // all 4 elems in same channel plane
  float m = meanv[o], r = rstdv[o];
  float4 v = *(const float4*)(mixed + e);
  float4 g;
  float z;
  z = (v.x - m) * r; g.x = 0.5f * z * (1.0f + erff(z * 0.70710678118654752f));
  z = (v.y - m) * r; g.y = 0.5f * z * (1.0f + erff(z * 0.70710678118654752f));
  z = (v.z - m) * r; g.z = 0.5f * z * (1.0f + erff(z * 0.70710678118654752f));
  z = (v.w - m) * r; g.w = 0.5f * z * (1.0f + erff(z * 0.70710678118654752f));
  *(float4*)(out + e) = g;
}

extern "C" void kernel_launch(void* const* d_in, const int* in_sizes, int n_in,
                              void* d_out, int out_size, void* d_ws, size_t ws_size,
                              hipStream_t stream) {
  const float* hk   = (const float*)d_in[0];   // local_hk [96,1,7,7]
  const float* x    = (const float*)d_in[1];   // x [32,96,112,112]
  const float* wmix = (const float*)d_in[2];   // w_mix [96,96]
  const float* bmix = (const float*)d_in[3];   // b_mix [96] (cancels in BN)
  (void)bmix;
  float* out = (float*)d_out;

  char* ws = (char*)d_ws;
  float* stats = (float*)ws;                   // sum[96], ssq[96], mean[96], rstd[96]
  float* wT    = (float*)(ws + 2048);          // 96*96 floats
  float* mixed = (float*)(ws + 40960);         // 38,535,168 floats (154 MB)

  hipMemsetAsync(stats, 0, 768, stream);       // zero sum+ssq each call

  k_transpose<<<36, 256, 0, stream>>>(wmix, wT);
  k_fused<<<1568, 256, 0, stream>>>(x, hk, wT, mixed);
  k_stats<<<dim3(32, 96), 256, 0, stream>>>(mixed, stats, stats + 96);
  k_finalize<<<1, 128, 0, stream>>>(stats, stats + 96, stats + 192, stats + 288);
  k_bngelu<<<37632, 256, 0, stream>>>(mixed, stats + 192, stats + 288, out);
}